// Round 11
// baseline (384.488 us; speedup 1.0000x reference)
//
#include <hip/hip_runtime.h>

typedef _Float16 f16;
typedef _Float16 f16x8 __attribute__((ext_vector_type(8)));
typedef _Float16 f16x4 __attribute__((ext_vector_type(4)));
typedef float    f32x4 __attribute__((ext_vector_type(4)));
typedef float    f32x16 __attribute__((ext_vector_type(16)));

#define MROWS 8192      // B*S
#define KDIM  1024      // D
#define SEQ   2048
#define HDIM  64
#define QKV_LD 3072     // fused QKV leading dim

#if __has_builtin(__builtin_amdgcn_exp2f)
#define EXP2(x) __builtin_amdgcn_exp2f(x)
#else
#define EXP2(x) exp2f(x)
#endif

#define AS1 __attribute__((address_space(1)))
#define AS3 __attribute__((address_space(3)))

// 5-bit row mix: lanes n, n+8, n+16, n+24 get distinct keys (kills 4-way conflicts)
__device__ __forceinline__ int swz5(int row) { return (row ^ (row >> 3)) & 7; }

// ---------------- merged prep: cast3 + wtrans4 + concat3 in ONE launch ----------------
// blocks [0, 24576): fp32->f16 cast of query/key/value (8192 blocks each)
// blocks [24576, 28672): transpose+cast of wq/wk/wv/wo (1024 blocks each)
// blocks [28672, 28684): bias concat (12 blocks)
__global__ __launch_bounds__(256) void prep_k(const float* __restrict__ q_,
                                              const float* __restrict__ k_,
                                              const float* __restrict__ v_,
                                              const float* __restrict__ w0,
                                              const float* __restrict__ w1,
                                              const float* __restrict__ w2,
                                              const float* __restrict__ w3,
                                              const float* __restrict__ bq,
                                              const float* __restrict__ bk,
                                              const float* __restrict__ bv,
                                              f16* __restrict__ X16,
                                              f16* __restrict__ qkvT,
                                              f16* __restrict__ woT,
                                              float* __restrict__ b3) {
  __shared__ float t[32][33];
  const int bid = blockIdx.x;
  const int tid = threadIdx.x;
  if (bid < 24576) {
    int y = bid >> 13;                       // 0..2
    int i = (bid & 8191) * 256 + tid;
    const float* src = (y == 0) ? q_ : (y == 1) ? k_ : v_;
    float4 v = ((const float4*)src)[i];
    f16x4 o = { (f16)v.x, (f16)v.y, (f16)v.z, (f16)v.w };
    *(f16x4*)&X16[(size_t)y * 8388608 + (size_t)i * 4] = o;
  } else if (bid < 28672) {
    int local = bid - 24576;
    int z  = local >> 10;                    // 0..3
    int by = ((local >> 5) & 31) * 32;
    int bx = (local & 31) * 32;
    const float* w = (z == 0) ? w0 : (z == 1) ? w1 : (z == 2) ? w2 : w3;
    f16* wt = (z == 3) ? woT : (qkvT + z * 1048576);
    int tx = tid & 31, ty = tid >> 5;        // ty 0..7
    #pragma unroll
    for (int i = ty; i < 32; i += 8) t[i][tx] = w[(size_t)(by + i) * KDIM + bx + tx];
    __syncthreads();
    #pragma unroll
    for (int i = ty; i < 32; i += 8) wt[(size_t)(bx + i) * KDIM + by + tx] = (f16)t[tx][i];
  } else {
    int i = (bid - 28672) * 256 + tid;
    float v;
    if (i < 1024) v = bq[i]; else if (i < 2048) v = bk[i - 1024]; else v = bv[i - 2048];
    b3[i] = v;
  }
}

// ---------------- out-GEMM (kept): C[M x Ncols] = A[M x K] * Bt[N x K]^T + bias ----------------
template<bool OUT_F16>
__global__ __launch_bounds__(256) void gemm_k(const f16* __restrict__ A0, size_t aStride,
                                              const f16* __restrict__ Bt,
                                              const float* __restrict__ bias,
                                              void* __restrict__ Cout, int ldc) {
  __shared__ f16 sA[128 * 64];
  __shared__ f16 sB[128 * 64];
  const int tid  = threadIdx.x;
  const int lane = tid & 63;
  const int r    = lane & 15;
  const int q    = lane >> 4;
  const int wave = tid >> 6;
  const int m0 = blockIdx.x * 128;
  const int ng = blockIdx.z * 1024 + blockIdx.y * 128;
  const int wm = (wave >> 1) * 64;
  const int wn = (wave & 1) * 64;
  const f16* A = A0 + (size_t)blockIdx.z * aStride;

  f32x4 acc[4][4];
  #pragma unroll
  for (int i = 0; i < 4; ++i)
    #pragma unroll
    for (int j = 0; j < 4; ++j) acc[i][j] = (f32x4){0.f, 0.f, 0.f, 0.f};

  for (int kt = 0; kt < KDIM; kt += 64) {
    #pragma unroll
    for (int issue = 0; issue < 4; ++issue) {
      int g   = issue * 256 + tid;
      int row = g >> 3;
      int csw = (g & 7) ^ (row & 7);
      const f16* gA = A  + (size_t)(m0 + row) * KDIM + kt + csw * 8;
      const f16* gB = Bt + (size_t)(ng + row) * KDIM + kt + csw * 8;
      int lb = __builtin_amdgcn_readfirstlane((issue * 256 + (tid & ~63)) * 16);
      __builtin_amdgcn_global_load_lds((const AS1 void*)gA,
                                       (AS3 void*)((char*)sA + lb), 16, 0, 0);
      __builtin_amdgcn_global_load_lds((const AS1 void*)gB,
                                       (AS3 void*)((char*)sB + lb), 16, 0, 0);
    }
    __syncthreads();
    #pragma unroll
    for (int kk = 0; kk < 64; kk += 32) {
      f16x8 af[4], bf[4];
      #pragma unroll
      for (int mi = 0; mi < 4; ++mi) {
        int row = wm + mi * 16 + r;
        int cs  = ((kk >> 3) + q) ^ (row & 7);
        af[mi] = *(const f16x8*)&sA[row * 64 + cs * 8];
      }
      #pragma unroll
      for (int ni = 0; ni < 4; ++ni) {
        int row = wn + ni * 16 + r;
        int cs  = ((kk >> 3) + q) ^ (row & 7);
        bf[ni] = *(const f16x8*)&sB[row * 64 + cs * 8];
      }
      #pragma unroll
      for (int mi = 0; mi < 4; ++mi)
        #pragma unroll
        for (int ni = 0; ni < 4; ++ni)
          acc[mi][ni] = __builtin_amdgcn_mfma_f32_16x16x32_f16(af[mi], bf[ni], acc[mi][ni], 0, 0, 0);
    }
    __syncthreads();
  }
  #pragma unroll
  for (int ni = 0; ni < 4; ++ni) {
    int col = ng + wn + ni * 16 + r;
    float bv = bias[col];
    #pragma unroll
    for (int mi = 0; mi < 4; ++mi) {
      int rowb = m0 + wm + mi * 16 + q * 4;
      #pragma unroll
      for (int reg = 0; reg < 4; ++reg) {
        float v = acc[mi][ni][reg] + bv;
        if constexpr (OUT_F16) ((f16*)Cout)[(size_t)(rowb + reg) * ldc + col] = (f16)v;
        else                   ((float*)Cout)[(size_t)(rowb + reg) * ldc + col] = v;
      }
    }
  }
}

// ---------------- QKV GEMM: 256^2 tile, BK=64, 8 waves, 8-phase counted-vmcnt schedule ----------------
// V-region blocks (by >= 8) write their output TRANSPOSED into QKV's OWN V column region
// via the bijection Vt(b,h,d,s) -> QKV[b*2048 + 2*(h*64+d) + (s>>10)][2048 + (s&1023)].
__global__ __launch_bounds__(512, 2) void gemm256_k(const f16* __restrict__ A0,
                                                    const f16* __restrict__ Bt,
                                                    const float* __restrict__ bias,
                                                    f16* __restrict__ Cout) {
  __shared__ f16 smem[65536];   // 128 KB
  const int tid  = threadIdx.x;
  const int lane = tid & 63;
  const int r    = lane & 15;
  const int q    = lane >> 4;
  const int wave = tid >> 6;    // 0..7
  const int wm   = wave >> 2;   // 0..1
  const int wn   = wave & 3;    // 0..3

  const int id  = blockIdx.x;
  const int swz = (id & 7) * 48 + (id >> 3);
  const int bx  = swz & 31;     // M tile
  const int by  = swz >> 5;     // N tile
  const int m0  = bx * 256;
  const int n0  = by * 256;
  const f16* A  = A0 + (size_t)(by >> 2) * 8388608;   // Q/K/V input slice

  const int srow0 = tid >> 3;           // rows 0..63
  const int srow1 = (512 + tid) >> 3;   // rows 64..127
  const int sg0 = (tid & 7) ^ (srow0 & 7);
  const int sg1 = (tid & 7) ^ (srow1 & 7);
  const f16* gA0 = A  + (size_t)(m0 + srow0) * KDIM + sg0 * 8;
  const f16* gA1 = A  + (size_t)(m0 + srow1) * KDIM + sg1 * 8;
  const f16* gB0 = Bt + (size_t)(n0 + srow0) * KDIM + sg0 * 8;
  const f16* gB1 = Bt + (size_t)(n0 + srow1) * KDIM + sg1 * 8;
  const int lb0 = __builtin_amdgcn_readfirstlane((tid & ~63) * 16);
  const int lb1 = __builtin_amdgcn_readfirstlane((512 + (tid & ~63)) * 16);

  auto issueA = [&](int s, int hi) {    // A half 'hi' of K-tile s -> buf (s&1)
    char* base = (char*)smem + (s & 1) * 65536 + hi * 16384;
    const f16* s0 = gA0 + (size_t)hi * (128 * KDIM) + s * 64;
    const f16* s1 = gA1 + (size_t)hi * (128 * KDIM) + s * 64;
    __builtin_amdgcn_global_load_lds((const AS1 void*)s0, (AS3 void*)(base + lb0), 16, 0, 0);
    __builtin_amdgcn_global_load_lds((const AS1 void*)s1, (AS3 void*)(base + lb1), 16, 0, 0);
  };
  auto issueB = [&](int s, int hi) {
    char* base = (char*)smem + (s & 1) * 65536 + 32768 + hi * 16384;
    const f16* s0 = gB0 + (size_t)hi * (128 * KDIM) + s * 64;
    const f16* s1 = gB1 + (size_t)hi * (128 * KDIM) + s * 64;
    __builtin_amdgcn_global_load_lds((const AS1 void*)s0, (AS3 void*)(base + lb0), 16, 0, 0);
    __builtin_amdgcn_global_load_lds((const AS1 void*)s1, (AS3 void*)(base + lb1), 16, 0, 0);
  };

  auto readA = [&](int s, int qa, f16x8 (&af)[4][2]) {
    const f16* rg = smem + (s & 1) * 32768 + qa * 8192;          // elements
    #pragma unroll
    for (int mi = 0; mi < 4; ++mi) {
      int rl = wm * 64 + mi * 16 + r;
      #pragma unroll
      for (int kk2 = 0; kk2 < 2; ++kk2) {
        int g = kk2 * 4 + q;
        af[mi][kk2] = *(const f16x8*)&rg[rl * 64 + ((g ^ (rl & 7)) * 8)];
      }
    }
  };
  auto readB = [&](int s, int qb, f16x8 (&bf)[2][2]) {
    const f16* rg = smem + (s & 1) * 32768 + 16384 + qb * 8192;  // elements
    #pragma unroll
    for (int ni = 0; ni < 2; ++ni) {
      int rl = wn * 32 + ni * 16 + r;
      #pragma unroll
      for (int kk2 = 0; kk2 < 2; ++kk2) {
        int g = kk2 * 4 + q;
        bf[ni][kk2] = *(const f16x8*)&rg[rl * 64 + ((g ^ (rl & 7)) * 8)];
      }
    }
  };

  f32x4 acc[8][4];
  #pragma unroll
  for (int i = 0; i < 8; ++i)
    #pragma unroll
    for (int j = 0; j < 4; ++j) acc[i][j] = (f32x4){0.f, 0.f, 0.f, 0.f};

  auto mmaQ = [&](f16x8 (&af)[4][2], f16x8 (&bf)[2][2], int qa, int qb) {
    __builtin_amdgcn_s_setprio(1);
    #pragma unroll
    for (int kk2 = 0; kk2 < 2; ++kk2)
      #pragma unroll
      for (int mi = 0; mi < 4; ++mi)
        #pragma unroll
        for (int ni = 0; ni < 2; ++ni)
          acc[qa * 4 + mi][qb * 2 + ni] =
            __builtin_amdgcn_mfma_f32_16x16x32_f16(af[mi][kk2], bf[ni][kk2],
                                                   acc[qa * 4 + mi][qb * 2 + ni], 0, 0, 0);
    __builtin_amdgcn_s_setprio(0);
  };

  auto bar = [] {
    __builtin_amdgcn_sched_barrier(0);
    __builtin_amdgcn_s_barrier();
    __builtin_amdgcn_sched_barrier(0);
  };

  issueA(0, 0); issueB(0, 0); issueB(0, 1); issueA(0, 1);
  issueB(1, 0); issueA(1, 0); issueB(1, 1);
  asm volatile("s_waitcnt vmcnt(6)");
  bar();

  f16x8 alo[4][2], ahi[4][2], blo[2][2], bhi[2][2];
  #pragma unroll 1
  for (int s = 0; s < 16; ++s) {
    readA(s, 0, alo);
    readB(s, 0, blo);
    if (s + 1 < 16) issueA(s + 1, 1);
    bar();
    mmaQ(alo, blo, 0, 0);
    bar();
    readB(s, 1, bhi);
    if (s + 2 < 16) issueB(s + 2, 0);
    bar();
    mmaQ(alo, bhi, 0, 1);
    bar();
    readA(s, 1, ahi);
    if (s + 2 < 16) issueA(s + 2, 0);
    bar();
    mmaQ(ahi, bhi, 1, 1);
    bar();
    if (s + 2 < 16) issueB(s + 2, 1);
    if (s < 14)       { asm volatile("s_waitcnt vmcnt(6)"); }
    else if (s == 14) { asm volatile("s_waitcnt vmcnt(0)"); }
    bar();
    mmaQ(ahi, blo, 1, 0);
    bar();
  }

  if (by >= 8) {
    // V region: fused transpose, embedded in QKV's V columns.
    #pragma unroll
    for (int mi8 = 0; mi8 < 8; ++mi8) {
      int rowb = m0 + (mi8 >> 2) * 128 + wm * 64 + (mi8 & 3) * 16 + q * 4;  // mult of 4
      int bb = rowb >> 11, ss = rowb & 2047;
      #pragma unroll
      for (int ni4 = 0; ni4 < 4; ++ni4) {
        int col = n0 + (ni4 >> 1) * 128 + wn * 32 + (ni4 & 1) * 16 + r;  // 2048..3071
        int vcol = col - 2048;                                           // h*64 + d
        float bv = bias[col];
        f16x4 o = { (f16)(acc[mi8][ni4][0] + bv), (f16)(acc[mi8][ni4][1] + bv),
                    (f16)(acc[mi8][ni4][2] + bv), (f16)(acc[mi8][ni4][3] + bv) };
        size_t row2 = (size_t)bb * 2048 + 2 * vcol + (ss >> 10);
        *(f16x4*)&Cout[row2 * QKV_LD + 2048 + (ss & 1023)] = o;
      }
    }
  } else {
    #pragma unroll
    for (int mi8 = 0; mi8 < 8; ++mi8) {
      int rowb = m0 + (mi8 >> 2) * 128 + wm * 64 + (mi8 & 3) * 16 + q * 4;
      #pragma unroll
      for (int ni4 = 0; ni4 < 4; ++ni4) {
        int col = n0 + (ni4 >> 1) * 128 + wn * 32 + (ni4 & 1) * 16 + r;
        float bv = bias[col];
        #pragma unroll
        for (int reg = 0; reg < 4; ++reg)
          Cout[(size_t)(rowb + reg) * QKV_LD + col] = (f16)(acc[mi8][ni4][reg] + bv);
      }
    }
  }
}

// ---------------- flash attention: 8 waves / 256 q-rows, T15 exp/QK overlap ----------------
// NEW vs round 10: software-pipeline the per-wave serial chain. Body of tile t:
//   syncthreads -> stage(t+2) -> QK-half0(t+1) -> exp-half0(t) -> QK-half1(t+1)
//   -> exp-half1(t) -> PV(t)
// so the exp/cvt VALU work of tile t runs while tile t+1's QK MFMAs execute.
// 4 LDS buffers (64 KB, free: grid caps at 2 blocks/CU), loop unrolled x4 so ALL
// buffer offsets are compile-time literals (round-9 lesson). Interleaved QK/exp
// halves keep peak VGPR ~116 (< 128 -> 4 waves/SIMD preserved; round-5 lesson).
// Safety: per-tile __syncthreads drains stage(t+1) (issued a full tile earlier ->
// no latency exposure) and orders stage(t+2)'s overwrite of buf((t+2)%4), whose
// last reader (tile t-2) finished two barriers ago.
__global__ __launch_bounds__(512) void attn_k(const f16* __restrict__ qkv,
                                              f16* __restrict__ ctx) {
  __shared__ f16 smem[32768];            // 64 KB: 4 bufs x 8192 elems (K 4096 | V 4096)
  const int tid  = threadIdx.x;
  const int lane = tid & 63;
  const int wave = tid >> 6;             // 0..7
  const int n    = lane & 31;            // q-row within wave
  const int q32  = lane >> 5;
  // raw linear id = x + 8y + 128z; qt = high 3 bits, (h,b) = low 6 bits
  const int flat = blockIdx.x + (blockIdx.y << 3) + (blockIdx.z << 7);
  const int qt = flat >> 6;              // 0..7
  const int hb = flat & 63;
  const int h  = hb & 15;
  const int b  = hb >> 4;

  const f16* Qb  = qkv + (size_t)b * SEQ * QKV_LD + h * HDIM;
  const int qrow = qt * 256 + wave * 32 + n;

  f16x8 qf[4];
  {
    const f16* qp = Qb + (size_t)qrow * QKV_LD + q32 * 8;
    const f16 sc = (f16)(0.125f * 1.44269504f);
    #pragma unroll
    for (int cc = 0; cc < 4; ++cc) qf[cc] = *(const f16x8*)(qp + cc * 16) * sc;
  }

  // staging: 512 threads cover 64 rows x 64 cols in ONE issue per region
  const int r0 = tid >> 3, c0 = tid & 7;
  const f16* gK0 = Qb + 1024 + (size_t)r0 * QKV_LD + (c0 ^ swz5(r0)) * 8;
  const f16* VtB = qkv + ((size_t)b * 2048 + 2 * (h * HDIM + r0)) * QKV_LD + 2048
                   + (c0 ^ swz5(r0)) * 8;
  const int lb = __builtin_amdgcn_readfirstlane((tid & ~63) * 16);   // 0..7168

  int vt_t = 0;                          // tile counter for V addressing
  auto stage = [&](int bufbyte) {
    char* base = (char*)smem + bufbyte + lb;
    const f16* gV = VtB + (size_t)(vt_t >> 4) * QKV_LD + (vt_t & 15) * 64;
    __builtin_amdgcn_global_load_lds((const AS1 void*)gK0, (AS3 void*)(base), 16, 0, 0);
    __builtin_amdgcn_global_load_lds((const AS1 void*)gV, (AS3 void*)(base + 8192), 16, 0, 0);
    gK0 += 64 * QKV_LD; ++vt_t;
  };

  f32x16 ot[2];
  #pragma unroll
  for (int db = 0; db < 2; ++db)
    #pragma unroll
    for (int i = 0; i < 16; ++i) ot[db][i] = 0.f;
  float ls = 0.f;

  // one QK half: 4 MFMAs for key-row group kc into st
  auto qkh = [&](int bufe, int kc, f32x16& st) {
    const f16* sK = smem + bufe;           // [64 key][64 d], swz5 granules
    #pragma unroll
    for (int i = 0; i < 16; ++i) st[i] = -2.8853901817f;   // -2*log2(e)
    int row = kc * 32 + n;
    __builtin_amdgcn_s_setprio(1);
    #pragma unroll
    for (int cc = 0; cc < 4; ++cc) {
      f16x8 kf = *(const f16x8*)&sK[row * 64 + (((cc * 2 + q32) ^ swz5(row)) * 8)];
      st = __builtin_amdgcn_mfma_f32_32x32x16_f16(kf, qf[cc], st, 0, 0, 0);
    }
    __builtin_amdgcn_s_setprio(0);
  };

  // one exp half: 16 exps + ls + pack into pg[0..3]
  auto exph = [&](f32x16& st, f16x4* pg) {
    #pragma unroll
    for (int g = 0; g < 4; ++g) {
      float e0 = EXP2(st[4 * g + 0]);
      float e1 = EXP2(st[4 * g + 1]);
      float e2 = EXP2(st[4 * g + 2]);
      float e3 = EXP2(st[4 * g + 3]);
      ls += (e0 + e1) + (e2 + e3);
      pg[g] = (f16x4){ (f16)e0, (f16)e1, (f16)e2, (f16)e3 };
    }
  };

  auto pv = [&](f16x4 (&p)[2][4], int bufe) {
    const f16* sV = smem + bufe + 4096;    // [64 d][64 key], swz5 granules
    __builtin_amdgcn_s_setprio(1);
    #pragma unroll
    for (int db = 0; db < 2; ++db) {
      int row = db * 32 + n;
      int fr = swz5(row);
      const f16* vrow = &sV[row * 64];
      #pragma unroll
      for (int cc = 0; cc < 4; ++cc) {
        int hg = (2 * cc) ^ fr;
        f16x4 vlo = *(const f16x4*)&vrow[hg * 8 + q32 * 4];
        f16x4 vhi = *(const f16x4*)&vrow[(hg ^ 1) * 8 + q32 * 4];
        f16x8 vf = __builtin_shufflevector(vlo, vhi, 0, 1, 2, 3, 4, 5, 6, 7);
        f16x8 pf = __builtin_shufflevector(p[cc >> 1][2 * (cc & 1)],
                                           p[cc >> 1][2 * (cc & 1) + 1],
                                           0, 1, 2, 3, 4, 5, 6, 7);
        ot[db] = __builtin_amdgcn_mfma_f32_32x32x16_f16(vf, pf, ot[db], 0, 0, 0);
      }
    }
    __builtin_amdgcn_s_setprio(0);
  };

  // body(t): curE = buf(t%4) elems, nxtE = buf((t+1)%4) elems, stgB = buf((t+2)%4) bytes
  auto body = [&](int curE, int nxtE, int stgB, int t,
                  f32x16& c0, f32x16& c1, f32x16& n0v, f32x16& n1v) {
    __syncthreads();                       // stage(t+1) complete; buf(t+2) free
    if (t + 2 < 32) stage(stgB);
    f16x4 p[2][4];
    if (t + 1 < 32) qkh(nxtE, 0, n0v);     // QK(t+1) half0 fills MFMA pipe...
    exph(c0, p[0]);                        // ...while exp(t) half0 runs on VALU
    if (t + 1 < 32) qkh(nxtE, 1, n1v);
    exph(c1, p[1]);
    pv(p, curE);
  };

  // prologue: tiles 0,1 staged; QK(0)
  stage(0);
  stage(16384);
  __syncthreads();
  f32x16 sA0, sA1, sB0, sB1;
  qkh(0, 0, sA0);
  qkh(0, 1, sA1);

  #pragma unroll 1
  for (int k = 0; k < 8; ++k) {
    int t0 = k * 4;
    body(0,     8192,  32768, t0 + 0, sA0, sA1, sB0, sB1);
    body(8192,  16384, 49152, t0 + 1, sB0, sB1, sA0, sA1);
    body(16384, 24576, 0,     t0 + 2, sA0, sA1, sB0, sB1);
    body(24576, 0,     16384, t0 + 3, sB0, sB1, sA0, sA1);
  }

  ls += __shfl_xor(ls, 32);
  float inv = 1.0f / ls;

  // Ot -> sO[256 qrow][64 d] (f16, swz5) occupies bufs 0-1 (bytes 0..32767);
  // last computes read bufs 2-3 only -> no overlap, but barrier-order the reads.
  __syncthreads();
  f16* sO = smem;
  int nl = wave * 32 + n;                // 0..255
  int fo = swz5(nl);
  #pragma unroll
  for (int db = 0; db < 2; ++db)
    #pragma unroll
    for (int g = 0; g < 4; ++g) {
      f16x4 o = { (f16)(ot[db][4 * g + 0] * inv), (f16)(ot[db][4 * g + 1] * inv),
                  (f16)(ot[db][4 * g + 2] * inv), (f16)(ot[db][4 * g + 3] * inv) };
      *(f16x4*)&sO[nl * 64 + (((db * 4 + g) ^ fo) * 8) + q32 * 4] = o;
    }
  __syncthreads();
  #pragma unroll
  for (int issue = 0; issue < 4; ++issue) {
    int g = issue * 512 + tid;           // 0..2047
    int rr = g >> 3, sg = g & 7;         // rr 0..255
    f16x8 v = *(const f16x8*)&sO[rr * 64 + ((sg ^ swz5(rr)) * 8)];
    *(f16x8*)&ctx[(size_t)(b * SEQ + qt * 256 + rr) * KDIM + h * HDIM + sg * 8] = v;
  }
}

// ---------------- launch ----------------
// ws layout (bytes):
//   0        : X16 slot0 (16.78MB)  -> later: ctx (f16)
//   16777216 : X16 slot1 (16.78MB)
//   33554432 : X16 slot2 (16.78MB)
//   50331648 : qkvT  (3072x1024 f16, 6MB)
//   56623104 : woT   (1024x1024 f16, 2MB)
//   58720256 : b3    (3072 f32)
//   58736640 : QKV   (8192x3072 f16, 48MB; V cols hold the transposed-V embedding)
extern "C" void kernel_launch(void* const* d_in, const int* in_sizes, int n_in,
                              void* d_out, int out_size, void* d_ws, size_t ws_size,
                              hipStream_t stream) {
  (void)in_sizes; (void)n_in; (void)out_size; (void)ws_size;
  const float* query = (const float*)d_in[0];
  const float* key_  = (const float*)d_in[1];
  const float* value = (const float*)d_in[2];
  const float* wq = (const float*)d_in[3];
  const float* bq = (const float*)d_in[4];
  const float* wk = (const float*)d_in[5];
  const float* bk = (const float*)d_in[6];
  const float* wv = (const float*)d_in[7];
  const float* bv = (const float*)d_in[8];
  const float* wo = (const float*)d_in[9];
  const float* bo = (const float*)d_in[10];
  float* out = (float*)d_out;

  char* ws = (char*)d_ws;
  f16*   X16  = (f16*)(ws);
  f16*   qkvT = (f16*)(ws + 50331648);
  f16*   woT  = (f16*)(ws + 56623104);
  float* b3   = (float*)(ws + 58720256);
  f16*   QKV  = (f16*)(ws + 58736640);
  f16*   ctx  = (f16*)(ws);                   // aliases X16 slot0 (dead after QKV GEMM)

  prep_k<<<dim3(28684), 256, 0, stream>>>(query, key_, value, wq, wk, wv, wo,
                                          bq, bk, bv, X16, qkvT, woT, b3);

  gemm256_k<<<dim3(384), 512, 0, stream>>>(X16, qkvT, b3, QKV);
  attn_k<<<dim3(8, 16, 4), 512, 0, stream>>>(QKV, ctx);
  gemm_k<false><<<dim3(64, 8, 1), 256, 0, stream>>>(ctx, (size_t)0, woT, bo, (void*)out, 1024);
}

// Round 12
// 326.506 us; speedup vs baseline: 1.1776x; 1.1776x over previous
//
#include <hip/hip_runtime.h>

typedef _Float16 f16;
typedef _Float16 f16x8 __attribute__((ext_vector_type(8)));
typedef _Float16 f16x4 __attribute__((ext_vector_type(4)));
typedef float    f32x4 __attribute__((ext_vector_type(4)));
typedef float    f32x16 __attribute__((ext_vector_type(16)));

#define MROWS 8192      // B*S
#define KDIM  1024      // D
#define SEQ   2048
#define HDIM  64
#define QKV_LD 3072     // fused QKV leading dim

#if __has_builtin(__builtin_amdgcn_exp2f)
#define EXP2(x) __builtin_amdgcn_exp2f(x)
#else
#define EXP2(x) exp2f(x)
#endif

#define AS1 __attribute__((address_space(1)))
#define AS3 __attribute__((address_space(3)))

// 5-bit row mix: lanes n, n+8, n+16, n+24 get distinct keys (kills 4-way conflicts)
__device__ __forceinline__ int swz5(int row) { return (row ^ (row >> 3)) & 7; }

// ---------------- merged prep: cast3 + wtrans4 + concat3 in ONE launch ----------------
__global__ __launch_bounds__(256) void prep_k(const float* __restrict__ q_,
                                              const float* __restrict__ k_,
                                              const float* __restrict__ v_,
                                              const float* __restrict__ w0,
                                              const float* __restrict__ w1,
                                              const float* __restrict__ w2,
                                              const float* __restrict__ w3,
                                              const float* __restrict__ bq,
                                              const float* __restrict__ bk,
                                              const float* __restrict__ bv,
                                              f16* __restrict__ X16,
                                              f16* __restrict__ qkvT,
                                              f16* __restrict__ woT,
                                              float* __restrict__ b3) {
  __shared__ float t[32][33];
  const int bid = blockIdx.x;
  const int tid = threadIdx.x;
  if (bid < 24576) {
    int y = bid >> 13;                       // 0..2
    int i = (bid & 8191) * 256 + tid;
    const float* src = (y == 0) ? q_ : (y == 1) ? k_ : v_;
    float4 v = ((const float4*)src)[i];
    f16x4 o = { (f16)v.x, (f16)v.y, (f16)v.z, (f16)v.w };
    *(f16x4*)&X16[(size_t)y * 8388608 + (size_t)i * 4] = o;
  } else if (bid < 28672) {
    int local = bid - 24576;
    int z  = local >> 10;                    // 0..3
    int by = ((local >> 5) & 31) * 32;
    int bx = (local & 31) * 32;
    const float* w = (z == 0) ? w0 : (z == 1) ? w1 : (z == 2) ? w2 : w3;
    f16* wt = (z == 3) ? woT : (qkvT + z * 1048576);
    int tx = tid & 31, ty = tid >> 5;        // ty 0..7
    #pragma unroll
    for (int i = ty; i < 32; i += 8) t[i][tx] = w[(size_t)(by + i) * KDIM + bx + tx];
    __syncthreads();
    #pragma unroll
    for (int i = ty; i < 32; i += 8) wt[(size_t)(bx + i) * KDIM + by + tx] = (f16)t[tx][i];
  } else {
    int i = (bid - 28672) * 256 + tid;
    float v;
    if (i < 1024) v = bq[i]; else if (i < 2048) v = bk[i - 1024]; else v = bv[i - 2048];
    b3[i] = v;
  }
}

// ---------------- out-GEMM (kept): C[M x Ncols] = A[M x K] * Bt[N x K]^T + bias ----------------
template<bool OUT_F16>
__global__ __launch_bounds__(256) void gemm_k(const f16* __restrict__ A0, size_t aStride,
                                              const f16* __restrict__ Bt,
                                              const float* __restrict__ bias,
                                              void* __restrict__ Cout, int ldc) {
  __shared__ f16 sA[128 * 64];
  __shared__ f16 sB[128 * 64];
  const int tid  = threadIdx.x;
  const int lane = tid & 63;
  const int r    = lane & 15;
  const int q    = lane >> 4;
  const int wave = tid >> 6;
  const int m0 = blockIdx.x * 128;
  const int ng = blockIdx.z * 1024 + blockIdx.y * 128;
  const int wm = (wave >> 1) * 64;
  const int wn = (wave & 1) * 64;
  const f16* A = A0 + (size_t)blockIdx.z * aStride;

  f32x4 acc[4][4];
  #pragma unroll
  for (int i = 0; i < 4; ++i)
    #pragma unroll
    for (int j = 0; j < 4; ++j) acc[i][j] = (f32x4){0.f, 0.f, 0.f, 0.f};

  for (int kt = 0; kt < KDIM; kt += 64) {
    #pragma unroll
    for (int issue = 0; issue < 4; ++issue) {
      int g   = issue * 256 + tid;
      int row = g >> 3;
      int csw = (g & 7) ^ (row & 7);
      const f16* gA = A  + (size_t)(m0 + row) * KDIM + kt + csw * 8;
      const f16* gB = Bt + (size_t)(ng + row) * KDIM + kt + csw * 8;
      int lb = __builtin_amdgcn_readfirstlane((issue * 256 + (tid & ~63)) * 16);
      __builtin_amdgcn_global_load_lds((const AS1 void*)gA,
                                       (AS3 void*)((char*)sA + lb), 16, 0, 0);
      __builtin_amdgcn_global_load_lds((const AS1 void*)gB,
                                       (AS3 void*)((char*)sB + lb), 16, 0, 0);
    }
    __syncthreads();
    #pragma unroll
    for (int kk = 0; kk < 64; kk += 32) {
      f16x8 af[4], bf[4];
      #pragma unroll
      for (int mi = 0; mi < 4; ++mi) {
        int row = wm + mi * 16 + r;
        int cs  = ((kk >> 3) + q) ^ (row & 7);
        af[mi] = *(const f16x8*)&sA[row * 64 + cs * 8];
      }
      #pragma unroll
      for (int ni = 0; ni < 4; ++ni) {
        int row = wn + ni * 16 + r;
        int cs  = ((kk >> 3) + q) ^ (row & 7);
        bf[ni] = *(const f16x8*)&sB[row * 64 + cs * 8];
      }
      #pragma unroll
      for (int mi = 0; mi < 4; ++mi)
        #pragma unroll
        for (int ni = 0; ni < 4; ++ni)
          acc[mi][ni] = __builtin_amdgcn_mfma_f32_16x16x32_f16(af[mi], bf[ni], acc[mi][ni], 0, 0, 0);
    }
    __syncthreads();
  }
  #pragma unroll
  for (int ni = 0; ni < 4; ++ni) {
    int col = ng + wn + ni * 16 + r;
    float bv = bias[col];
    #pragma unroll
    for (int mi = 0; mi < 4; ++mi) {
      int rowb = m0 + wm + mi * 16 + q * 4;
      #pragma unroll
      for (int reg = 0; reg < 4; ++reg) {
        float v = acc[mi][ni][reg] + bv;
        if constexpr (OUT_F16) ((f16*)Cout)[(size_t)(rowb + reg) * ldc + col] = (f16)v;
        else                   ((float*)Cout)[(size_t)(rowb + reg) * ldc + col] = v;
      }
    }
  }
}

// ---------------- QKV GEMM: 256^2 tile, BK=64, 8 waves, 8-phase counted-vmcnt schedule ----------------
// V-region blocks (by >= 8) write their output TRANSPOSED into QKV's OWN V column region
// via the bijection Vt(b,h,d,s) -> QKV[b*2048 + 2*(h*64+d) + (s>>10)][2048 + (s&1023)].
// NEW vs round 10: COALESCED EPILOGUE. Old: Q/K blocks = scalar 2B stores (~25% write
// eff), V blocks = 8B stores at 12KB lane stride (~12%). Now: acc -> LDS (dead 128KB
// buffer, bank-swizzled) -> barrier -> f16x8 16B fully-coalesced global stores.
__global__ __launch_bounds__(512, 2) void gemm256_k(const f16* __restrict__ A0,
                                                    const f16* __restrict__ Bt,
                                                    const float* __restrict__ bias,
                                                    f16* __restrict__ Cout) {
  __shared__ f16 smem[65536];   // 128 KB
  const int tid  = threadIdx.x;
  const int lane = tid & 63;
  const int r    = lane & 15;
  const int q    = lane >> 4;
  const int wave = tid >> 6;    // 0..7
  const int wm   = wave >> 2;   // 0..1
  const int wn   = wave & 3;    // 0..3

  const int id  = blockIdx.x;
  const int swz = (id & 7) * 48 + (id >> 3);
  const int bx  = swz & 31;     // M tile
  const int by  = swz >> 5;     // N tile
  const int m0  = bx * 256;
  const int n0  = by * 256;
  const f16* A  = A0 + (size_t)(by >> 2) * 8388608;   // Q/K/V input slice

  const int srow0 = tid >> 3;           // rows 0..63
  const int srow1 = (512 + tid) >> 3;   // rows 64..127
  const int sg0 = (tid & 7) ^ (srow0 & 7);
  const int sg1 = (tid & 7) ^ (srow1 & 7);
  const f16* gA0 = A  + (size_t)(m0 + srow0) * KDIM + sg0 * 8;
  const f16* gA1 = A  + (size_t)(m0 + srow1) * KDIM + sg1 * 8;
  const f16* gB0 = Bt + (size_t)(n0 + srow0) * KDIM + sg0 * 8;
  const f16* gB1 = Bt + (size_t)(n0 + srow1) * KDIM + sg1 * 8;
  const int lb0 = __builtin_amdgcn_readfirstlane((tid & ~63) * 16);
  const int lb1 = __builtin_amdgcn_readfirstlane((512 + (tid & ~63)) * 16);

  auto issueA = [&](int s, int hi) {    // A half 'hi' of K-tile s -> buf (s&1)
    char* base = (char*)smem + (s & 1) * 65536 + hi * 16384;
    const f16* s0 = gA0 + (size_t)hi * (128 * KDIM) + s * 64;
    const f16* s1 = gA1 + (size_t)hi * (128 * KDIM) + s * 64;
    __builtin_amdgcn_global_load_lds((const AS1 void*)s0, (AS3 void*)(base + lb0), 16, 0, 0);
    __builtin_amdgcn_global_load_lds((const AS1 void*)s1, (AS3 void*)(base + lb1), 16, 0, 0);
  };
  auto issueB = [&](int s, int hi) {
    char* base = (char*)smem + (s & 1) * 65536 + 32768 + hi * 16384;
    const f16* s0 = gB0 + (size_t)hi * (128 * KDIM) + s * 64;
    const f16* s1 = gB1 + (size_t)hi * (128 * KDIM) + s * 64;
    __builtin_amdgcn_global_load_lds((const AS1 void*)s0, (AS3 void*)(base + lb0), 16, 0, 0);
    __builtin_amdgcn_global_load_lds((const AS1 void*)s1, (AS3 void*)(base + lb1), 16, 0, 0);
  };

  auto readA = [&](int s, int qa, f16x8 (&af)[4][2]) {
    const f16* rg = smem + (s & 1) * 32768 + qa * 8192;          // elements
    #pragma unroll
    for (int mi = 0; mi < 4; ++mi) {
      int rl = wm * 64 + mi * 16 + r;
      #pragma unroll
      for (int kk2 = 0; kk2 < 2; ++kk2) {
        int g = kk2 * 4 + q;
        af[mi][kk2] = *(const f16x8*)&rg[rl * 64 + ((g ^ (rl & 7)) * 8)];
      }
    }
  };
  auto readB = [&](int s, int qb, f16x8 (&bf)[2][2]) {
    const f16* rg = smem + (s & 1) * 32768 + 16384 + qb * 8192;  // elements
    #pragma unroll
    for (int ni = 0; ni < 2; ++ni) {
      int rl = wn * 32 + ni * 16 + r;
      #pragma unroll
      for (int kk2 = 0; kk2 < 2; ++kk2) {
        int g = kk2 * 4 + q;
        bf[ni][kk2] = *(const f16x8*)&rg[rl * 64 + ((g ^ (rl & 7)) * 8)];
      }
    }
  };

  f32x4 acc[8][4];
  #pragma unroll
  for (int i = 0; i < 8; ++i)
    #pragma unroll
    for (int j = 0; j < 4; ++j) acc[i][j] = (f32x4){0.f, 0.f, 0.f, 0.f};

  auto mmaQ = [&](f16x8 (&af)[4][2], f16x8 (&bf)[2][2], int qa, int qb) {
    __builtin_amdgcn_s_setprio(1);
    #pragma unroll
    for (int kk2 = 0; kk2 < 2; ++kk2)
      #pragma unroll
      for (int mi = 0; mi < 4; ++mi)
        #pragma unroll
        for (int ni = 0; ni < 2; ++ni)
          acc[qa * 4 + mi][qb * 2 + ni] =
            __builtin_amdgcn_mfma_f32_16x16x32_f16(af[mi][kk2], bf[ni][kk2],
                                                   acc[qa * 4 + mi][qb * 2 + ni], 0, 0, 0);
    __builtin_amdgcn_s_setprio(0);
  };

  auto bar = [] {
    __builtin_amdgcn_sched_barrier(0);
    __builtin_amdgcn_s_barrier();
    __builtin_amdgcn_sched_barrier(0);
  };

  issueA(0, 0); issueB(0, 0); issueB(0, 1); issueA(0, 1);
  issueB(1, 0); issueA(1, 0); issueB(1, 1);
  asm volatile("s_waitcnt vmcnt(6)");
  bar();

  f16x8 alo[4][2], ahi[4][2], blo[2][2], bhi[2][2];
  #pragma unroll 1
  for (int s = 0; s < 16; ++s) {
    readA(s, 0, alo);
    readB(s, 0, blo);
    if (s + 1 < 16) issueA(s + 1, 1);
    bar();
    mmaQ(alo, blo, 0, 0);
    bar();
    readB(s, 1, bhi);
    if (s + 2 < 16) issueB(s + 2, 0);
    bar();
    mmaQ(alo, bhi, 0, 1);
    bar();
    readA(s, 1, ahi);
    if (s + 2 < 16) issueA(s + 2, 0);
    bar();
    mmaQ(ahi, bhi, 1, 1);
    bar();
    if (s + 2 < 16) issueB(s + 2, 1);
    if (s < 14)       { asm volatile("s_waitcnt vmcnt(6)"); }
    else if (s == 14) { asm volatile("s_waitcnt vmcnt(0)"); }
    bar();
    mmaQ(ahi, blo, 1, 0);
    bar();
  }
  // K-loop done; after final bar() all waves are past their last LDS read -> smem is free.

  f16* sC = smem;   // 256 x 256 f16 staging tile (128 KB)

  if (by >= 8) {
    // ---- V blocks: stage as sC[vcol 0..255][ss 0..255], granule-8 XOR swizzle ----
    #pragma unroll
    for (int mi8 = 0; mi8 < 8; ++mi8) {
      int ssl = (mi8 >> 2) * 128 + wm * 64 + (mi8 & 3) * 16 + q * 4;   // local s, +reg
      #pragma unroll
      for (int ni4 = 0; ni4 < 4; ++ni4) {
        int vcl = (ni4 >> 1) * 128 + wn * 32 + (ni4 & 1) * 16 + r;     // local vcol
        float bv = bias[n0 + vcl];
        f16x4 o = { (f16)(acc[mi8][ni4][0] + bv), (f16)(acc[mi8][ni4][1] + bv),
                    (f16)(acc[mi8][ni4][2] + bv), (f16)(acc[mi8][ni4][3] + bv) };
        *(f16x4*)&sC[vcl * 256 + (ssl ^ ((vcl & 7) << 3))] = o;
      }
    }
    __syncthreads();
    // coalesced stores: runs along ss are contiguous in QKV's V columns
    const int sbase = m0 & 1023;          // (ss & 1023) base (256-aligned block)
    const int c10   = (m0 & 2047) >> 10;  // ss>>10 (constant per block)
    const int bb    = m0 >> 11;
    #pragma unroll
    for (int it = 0; it < 16; ++it) {
      int vc  = it * 16 + (tid >> 5);     // local vcol 0..255
      int ss0 = (tid & 31) * 8;
      f16x8 v = *(const f16x8*)&sC[vc * 256 + (ss0 ^ ((vc & 7) << 3))];
      int vcolg = (n0 - 2048) + vc;       // h*64+d
      size_t row2 = (size_t)bb * 2048 + 2 * vcolg + c10;
      *(f16x8*)&Cout[row2 * QKV_LD + 2048 + sbase + ss0] = v;
    }
  } else {
    // ---- Q/K blocks: stage as sC[row 0..255][col 0..255], granule-16 XOR swizzle ----
    #pragma unroll
    for (int mi8 = 0; mi8 < 8; ++mi8) {
      int rl0 = (mi8 >> 2) * 128 + wm * 64 + (mi8 & 3) * 16 + q * 4;
      #pragma unroll
      for (int ni4 = 0; ni4 < 4; ++ni4) {
        int cl = (ni4 >> 1) * 128 + wn * 32 + (ni4 & 1) * 16 + r;
        float bv = bias[n0 + cl];
        #pragma unroll
        for (int reg = 0; reg < 4; ++reg) {
          int rl = rl0 + reg;
          sC[rl * 256 + (cl ^ ((rl & 7) << 4))] = (f16)(acc[mi8][ni4][reg] + bv);
        }
      }
    }
    __syncthreads();
    #pragma unroll
    for (int it = 0; it < 16; ++it) {
      int row = it * 16 + (tid >> 5);     // local row 0..255
      int c8  = (tid & 31) * 8;
      f16x8 v = *(const f16x8*)&sC[row * 256 + (c8 ^ ((row & 7) << 4))];
      *(f16x8*)&Cout[(size_t)(m0 + row) * QKV_LD + n0 + c8] = v;
    }
  }
}

// ---------------- flash attention: 8 waves / 256 q-rows per block (round-10 proven version) ----------------
// REVERT from round 11: T15 in-wave pipelining needed 4 live f32x16 score regs ->
// VGPR capped at 128 -> accumulator spills (WRITE 16->57MB, dur 91->146us). The
// register file can't hold a 2-tile score pipeline at this tile size; cross-wave
// TLP is the overlap mechanism. V read from the transposed embedding in QKV.
__global__ __launch_bounds__(512) void attn_k(const f16* __restrict__ qkv,
                                              f16* __restrict__ ctx) {
  __shared__ f16 smem[16384];            // 32 KB: buf0 f16[0,8192) = sK|sV, buf1 [8192,16384)
  const int tid  = threadIdx.x;
  const int lane = tid & 63;
  const int wave = tid >> 6;             // 0..7
  const int n    = lane & 31;            // q-row within wave
  const int q32  = lane >> 5;
  // raw linear id = x + 8y + 128z; qt = high 3 bits, (h,b) = low 6 bits
  const int flat = blockIdx.x + (blockIdx.y << 3) + (blockIdx.z << 7);
  const int qt = flat >> 6;              // 0..7
  const int hb = flat & 63;
  const int h  = hb & 15;
  const int b  = hb >> 4;

  const f16* Qb  = qkv + (size_t)b * SEQ * QKV_LD + h * HDIM;
  const int qrow = qt * 256 + wave * 32 + n;

  f16x8 qf[4];
  {
    const f16* qp = Qb + (size_t)qrow * QKV_LD + q32 * 8;
    const f16 sc = (f16)(0.125f * 1.44269504f);
    #pragma unroll
    for (int cc = 0; cc < 4; ++cc) qf[cc] = *(const f16x8*)(qp + cc * 16) * sc;
  }

  // staging: 512 threads cover 64 rows x 64 cols in ONE issue per region
  const int r0 = tid >> 3, c0 = tid & 7;
  const f16* gK0 = Qb + 1024 + (size_t)r0 * QKV_LD + (c0 ^ swz5(r0)) * 8;
  const f16* VtB = qkv + ((size_t)b * 2048 + 2 * (h * HDIM + r0)) * QKV_LD + 2048
                   + (c0 ^ swz5(r0)) * 8;
  const int lb = __builtin_amdgcn_readfirstlane((tid & ~63) * 16);   // 0..7168

  int vt_t = 0;                          // tile counter for V addressing
  auto stage = [&](int bufbyte) {
    char* base = (char*)smem + bufbyte + lb;
    const f16* gV = VtB + (size_t)(vt_t >> 4) * QKV_LD + (vt_t & 15) * 64;
    __builtin_amdgcn_global_load_lds((const AS1 void*)gK0, (AS3 void*)(base), 16, 0, 0);
    __builtin_amdgcn_global_load_lds((const AS1 void*)gV, (AS3 void*)(base + 8192), 16, 0, 0);
    gK0 += 64 * QKV_LD; ++vt_t;
  };

  f32x16 ot[2];
  #pragma unroll
  for (int db = 0; db < 2; ++db)
    #pragma unroll
    for (int i = 0; i < 16; ++i) ot[db][i] = 0.f;
  float ls = 0.f;

  auto compute = [&](int bufe) {           // bufe in f16 elements
    const f16* sK = smem + bufe;           // [64 key][64 d], swz5 granules
    const f16* sV = smem + bufe + 4096;    // [64 d][64 key], swz5 granules
    f16x4 p[2][4];
    #pragma unroll
    for (int kc = 0; kc < 2; ++kc) {
      f32x16 st;
      #pragma unroll
      for (int i = 0; i < 16; ++i) st[i] = -2.8853901817f;   // -2*log2(e)
      __builtin_amdgcn_s_setprio(1);
      #pragma unroll
      for (int cc = 0; cc < 4; ++cc) {
        int row = kc * 32 + n;
        f16x8 kf = *(const f16x8*)&sK[row * 64 + (((cc * 2 + q32) ^ swz5(row)) * 8)];
        st = __builtin_amdgcn_mfma_f32_32x32x16_f16(kf, qf[cc], st, 0, 0, 0);
      }
      __builtin_amdgcn_s_setprio(0);
      #pragma unroll
      for (int g = 0; g < 4; ++g) {
        float e0 = EXP2(st[4 * g + 0]);
        float e1 = EXP2(st[4 * g + 1]);
        float e2 = EXP2(st[4 * g + 2]);
        float e3 = EXP2(st[4 * g + 3]);
        ls += (e0 + e1) + (e2 + e3);
        p[kc][g] = (f16x4){ (f16)e0, (f16)e1, (f16)e2, (f16)e3 };
      }
    }
    __builtin_amdgcn_s_setprio(1);
    #pragma unroll
    for (int db = 0; db < 2; ++db) {
      int row = db * 32 + n;
      int fr = swz5(row);
      const f16* vrow = &sV[row * 64];
      #pragma unroll
      for (int cc = 0; cc < 4; ++cc) {
        int hg = (2 * cc) ^ fr;
        f16x4 vlo = *(const f16x4*)&vrow[hg * 8 + q32 * 4];
        f16x4 vhi = *(const f16x4*)&vrow[(hg ^ 1) * 8 + q32 * 4];
        f16x8 vf = __builtin_shufflevector(vlo, vhi, 0, 1, 2, 3, 4, 5, 6, 7);
        f16x8 pf = __builtin_shufflevector(p[cc >> 1][2 * (cc & 1)],
                                           p[cc >> 1][2 * (cc & 1) + 1],
                                           0, 1, 2, 3, 4, 5, 6, 7);
        ot[db] = __builtin_amdgcn_mfma_f32_32x32x16_f16(vf, pf, ot[db], 0, 0, 0);
      }
    }
    __builtin_amdgcn_s_setprio(0);
  };

  stage(0);
  #pragma unroll 1
  for (int it = 0; it < 32; it += 2) {
    __syncthreads();
    stage(16384);
    compute(0);
    __syncthreads();
    if (it + 2 < 32) stage(0);
    compute(8192);
  }

  ls += __shfl_xor(ls, 32);
  float inv = 1.0f / ls;

  // Ot -> sO[256 qrow][64 d] (f16, swz5) spans BOTH buffers -> barrier first.
  __syncthreads();
  f16* sO = smem;
  int nl = wave * 32 + n;                // 0..255
  int fo = swz5(nl);
  #pragma unroll
  for (int db = 0; db < 2; ++db)
    #pragma unroll
    for (int g = 0; g < 4; ++g) {
      f16x4 o = { (f16)(ot[db][4 * g + 0] * inv), (f16)(ot[db][4 * g + 1] * inv),
                  (f16)(ot[db][4 * g + 2] * inv), (f16)(ot[db][4 * g + 3] * inv) };
      *(f16x4*)&sO[nl * 64 + (((db * 4 + g) ^ fo) * 8) + q32 * 4] = o;
    }
  __syncthreads();
  #pragma unroll
  for (int issue = 0; issue < 4; ++issue) {
    int g = issue * 512 + tid;           // 0..2047
    int rr = g >> 3, sg = g & 7;         // rr 0..255
    f16x8 v = *(const f16x8*)&sO[rr * 64 + ((sg ^ swz5(rr)) * 8)];
    *(f16x8*)&ctx[(size_t)(b * SEQ + qt * 256 + rr) * KDIM + h * HDIM + sg * 8] = v;
  }
}

// ---------------- launch ----------------
// ws layout (bytes):
//   0        : X16 slot0 (16.78MB)  -> later: ctx (f16)
//   16777216 : X16 slot1 (16.78MB)
//   33554432 : X16 slot2 (16.78MB)
//   50331648 : qkvT  (3072x1024 f16, 6MB)
//   56623104 : woT   (1024x1024 f16, 2MB)
//   58720256 : b3    (3072 f32)
//   58736640 : QKV   (8192x3072 f16, 48MB; V cols hold the transposed-V embedding)
extern "C" void kernel_launch(void* const* d_in, const int* in_sizes, int n_in,
                              void* d_out, int out_size, void* d_ws, size_t ws_size,
                              hipStream_t stream) {
  (void)in_sizes; (void)n_in; (void)out_size; (void)ws_size;
  const float* query = (const float*)d_in[0];
  const float* key_  = (const float*)d_in[1];
  const float* value = (const float*)d_in[2];
  const float* wq = (const float*)d_in[3];
  const float* bq = (const float*)d_in[4];
  const float* wk = (const float*)d_in[5];
  const float* bk = (const float*)d_in[6];
  const float* wv = (const float*)d_in[7];
  const float* bv = (const float*)d_in[8];
  const float* wo = (const float*)d_in[9];
  const float* bo = (const float*)d_in[10];
  float* out = (float*)d_out;

  char* ws = (char*)d_ws;
  f16*   X16  = (f16*)(ws);
  f16*   qkvT = (f16*)(ws + 50331648);
  f16*   woT  = (f16*)(ws + 56623104);
  float* b3   = (float*)(ws + 58720256);
  f16*   QKV  = (f16*)(ws + 58736640);
  f16*   ctx  = (f16*)(ws);                   // aliases X16 slot0 (dead after QKV GEMM)

  prep_k<<<dim3(28684), 256, 0, stream>>>(query, key_, value, wq, wk, wv, wo,
                                          bq, bk, bv, X16, qkvT, woT, b3);

  gemm256_k<<<dim3(384), 512, 0, stream>>>(X16, qkvT, b3, QKV);
  attn_k<<<dim3(8, 16, 4), 512, 0, stream>>>(QKV, ctx);
  gemm_k<false><<<dim3(64, 8, 1), 256, 0, stream>>>(ctx, (size_t)0, woT, bo, (void*)out, 1024);
}